// Round 5
// baseline (242.657 us; speedup 1.0000x reference)
//
#include <hip/hip_runtime.h>

// Fused GRU-vector-neuron cell, MI355X gfx950 — round 5.
// vs round 4 (238us, MfmaUtil 31, VALUBusy 40, 2.3e7 bank conflicts):
//  * Frag stride padded 512 -> 520 us (1040 B): bank class rotates +4 per
//    fragment -> staging/writeback writes spread over all slot classes.
//    (Reads are lane-contiguous b128 -> conflict-free at any stride.)
//  * Staging remap: thread = (node, c8-group, v|mv) -> full-16B-slot
//    ownership: 6x float4 loads + 12x ds_write_b128, no partial-slot packs.
//    64 B gap between v- and mv-tile pairs puts the two pointer groups on
//    complementary bank classes within each write instruction.
//  * us8 rebuild over padded slots.
// Numerics identical to rounds 2-4 (absmax 0.03125): split-bf16 hi/lo
// (3 MFMAs) on r -> delta -> K; plain bf16 for z and Q.

#define NN   100000
#define NT   16
#define NBLK (NN / NT)   // 6250, exact
#define PSZ  16384       // us per weight plane (128x128 bf16), global ws
#define FS   520         // us per fragment in LDS A-tiles (1040 B, 16B-pad)
#define TSZ  (12 * FS)   // us per A-tile (12 frags)
#define GAP  32          // us gap to decorrelate v/mv bank classes

typedef unsigned short us;
typedef us     us8    __attribute__((ext_vector_type(8)));
typedef __bf16 bf16x8 __attribute__((ext_vector_type(8)));
typedef float  f32x4  __attribute__((ext_vector_type(4)));

#define MFMA __builtin_amdgcn_mfma_f32_16x16x32_bf16

__device__ __forceinline__ us f2b(float f) {   // RNE, used in prep only
    union { float f; unsigned u; } x; x.f = f;
    return (us)((x.u + 0x7FFFu + ((x.u >> 16) & 1u)) >> 16);
}
__device__ __forceinline__ float b2f(us h) {
    union { unsigned u; float f; } x; x.u = ((unsigned)h) << 16;
    return x.f;
}

// ---- prep: W[c][o] fp32 -> bf16 hi/lo planes, fragment-major (dense 512) ----
__global__ void prep_weights(const float* __restrict__ Whz, const float* __restrict__ Wiz,
                             const float* __restrict__ Whr, const float* __restrict__ Wir,
                             const float* __restrict__ Whv, const float* __restrict__ Wiv,
                             const float* __restrict__ Wq,  const float* __restrict__ Wk,
                             us* __restrict__ ws) {
    const int mid = blockIdx.x >> 3;
    const int s = ((blockIdx.x & 7) << 8) + threadIdx.x;
    const float* W; int hp, lp;
    switch (mid) {
        case 0: W = Whz; hp = 0;  lp = -1; break;
        case 1: W = Wiz; hp = 1;  lp = -1; break;
        case 2: W = Whr; hp = 2;  lp = 3;  break;
        case 3: W = Wir; hp = 4;  lp = 5;  break;
        case 4: W = Whv; hp = 6;  lp = 7;  break;
        case 5: W = Wiv; hp = 8;  lp = 9;  break;
        case 6: W = Wq;  hp = 10; lp = -1; break;
        default: W = Wk; hp = 11; lp = 12; break;
    }
    const int f = s >> 6, l = s & 63;
    const int o  = (f >> 2) * 16 + (l & 15);
    const int c0 = (f & 3) * 32 + (l >> 4) * 8;
    us8 hi, lo;
#pragma unroll
    for (int j = 0; j < 8; ++j) {
        float x = W[(c0 + j) * 128 + o];
        us h = f2b(x);
        hi[j] = h;
        lo[j] = f2b(x - b2f(h));
    }
    *(us8*)(ws + hp * PSZ + s * 8) = hi;
    if (lp >= 0) *(us8*)(ws + lp * PSZ + s * 8) = lo;
}

// ---- B-fragment register preload: 4 kf x bf16x8 from a global plane ----
__device__ __forceinline__ void loadB4(const us* __restrict__ p, int wb, bf16x8* d) {
#pragma unroll
    for (int kf = 0; kf < 4; ++kf) d[kf] = *(const bf16x8*)(p + wb + kf * 512);
}

// zacc += Ah@Bz (plain); racc += Ah@Bh + Al@Bh + Ah@Bl (precise)
__device__ __forceinline__ void mm_zr(const us* __restrict__ Ah, const us* __restrict__ Al,
                                      const bf16x8* bz, const bf16x8* bh, const bf16x8* bl,
                                      f32x4* zacc, f32x4* racc, int ab) {
#pragma unroll
    for (int kf = 0; kf < 4; ++kf)
#pragma unroll
        for (int m = 0; m < 3; ++m) {
            bf16x8 ah = *(const bf16x8*)(Ah + (m * 4 + kf) * FS + ab);
            bf16x8 al = *(const bf16x8*)(Al + (m * 4 + kf) * FS + ab);
            zacc[m] = MFMA(ah, bz[kf], zacc[m], 0, 0, 0);
            racc[m] = MFMA(ah, bh[kf], racc[m], 0, 0, 0);
            racc[m] = MFMA(al, bh[kf], racc[m], 0, 0, 0);
            racc[m] = MFMA(ah, bl[kf], racc[m], 0, 0, 0);
        }
}
// acc += Ah@(Bh+Bl) + Al@Bh
__device__ __forceinline__ void mm_s(const us* __restrict__ Ah, const us* __restrict__ Al,
                                     const bf16x8* bh, const bf16x8* bl,
                                     f32x4* acc, int ab) {
#pragma unroll
    for (int kf = 0; kf < 4; ++kf)
#pragma unroll
        for (int m = 0; m < 3; ++m) {
            bf16x8 ah = *(const bf16x8*)(Ah + (m * 4 + kf) * FS + ab);
            bf16x8 al = *(const bf16x8*)(Al + (m * 4 + kf) * FS + ab);
            acc[m] = MFMA(ah, bh[kf], acc[m], 0, 0, 0);
            acc[m] = MFMA(al, bh[kf], acc[m], 0, 0, 0);
            acc[m] = MFMA(ah, bl[kf], acc[m], 0, 0, 0);
        }
}
// Q plain, K precise (shared D-frag reads)
__device__ __forceinline__ void mm_qk(const us* __restrict__ Dh, const us* __restrict__ Dl,
                                      const bf16x8* bq, const bf16x8* bh, const bf16x8* bl,
                                      f32x4* qacc, f32x4* kacc, int ab) {
#pragma unroll
    for (int kf = 0; kf < 4; ++kf)
#pragma unroll
        for (int m = 0; m < 3; ++m) {
            bf16x8 dh = *(const bf16x8*)(Dh + (m * 4 + kf) * FS + ab);
            bf16x8 dl = *(const bf16x8*)(Dl + (m * 4 + kf) * FS + ab);
            qacc[m] = MFMA(dh, bq[kf], qacc[m], 0, 0, 0);
            kacc[m] = MFMA(dh, bh[kf], kacc[m], 0, 0, 0);
            kacc[m] = MFMA(dl, bh[kf], kacc[m], 0, 0, 0);
            kacc[m] = MFMA(dh, bl[kf], kacc[m], 0, 0, 0);
        }
}

__global__ __launch_bounds__(512, 4) void gru_vn_fused(
    const float* __restrict__ v, const float* __restrict__ mv,
    const float* __restrict__ bz, const float* __restrict__ br,
    const us* __restrict__ ws, float* __restrict__ out)
{
    // A-tile pool: vth | vtl | GAP | mvh | mvl. Tile = 12 frags x 520 us.
    // TSZ bytes = 12480 ≡ 64 (mod 128) -> vtl's bank class is vth+4; the GAP
    // keeps mvh at class +4 vs vth so simultaneous v/mv writes interleave.
    __shared__ __align__(16) us pool[4 * TSZ + GAP];
    __shared__ __align__(16) float r_t[128 * 17];       // r fp32, [c*17 + i]

    us* const vth = pool;
    us* const vtl = pool + TSZ;
    us* const mvh = pool + 2 * TSZ + GAP;
    us* const mvl = pool + 3 * TSZ + GAP;

    const int tid  = threadIdx.x;
    const int lane = tid & 63;
    const int wave = tid >> 6;
    const int arow = lane & 15;
    const int bo   = wave * 16 + arow;       // output channel
    const int rsub = (lane >> 4) * 4;        // C-frag row offset
    const int ab   = lane * 8;               // A-frag lane offset (us)
    const int wb   = wave * 2048 + lane * 8; // B-frag base in ws (us), +kf*512
    const int n0   = blockIdx.x * NT;

    const us* pWhz  = ws;            const us* pWiz  = ws + 1 * PSZ;
    const us* pWhrh = ws + 2 * PSZ;  const us* pWhrl = ws + 3 * PSZ;
    const us* pWirh = ws + 4 * PSZ;  const us* pWirl = ws + 5 * PSZ;
    const us* pWhvh = ws + 6 * PSZ;  const us* pWhvl = ws + 7 * PSZ;
    const us* pWivh = ws + 8 * PSZ;  const us* pWivl = ws + 9 * PSZ;
    const us* pWq   = ws + 10 * PSZ; const us* pWkh  = ws + 11 * PSZ;
    const us* pWkl  = ws + 12 * PSZ;

    // ---- stage v, m_v (hi/lo): thread = (node, c8-group, v|mv) ----
    {
        const int which = tid & 1;           // 0 -> v, 1 -> mv
        const int c8    = (tid >> 1) & 15;   // 8-channel group
        const int ind   = tid >> 5;          // node 0..15
        const float* src = (which ? mv : v) + (size_t)(n0 + ind) * 384 + c8 * 24;
        float x[24];
#pragma unroll
        for (int t = 0; t < 6; ++t) *(float4*)(x + 4 * t) = *(const float4*)(src + 4 * t);
        us* const dh = which ? mvh : vth;
        us* const dl = which ? mvl : vtl;
        const int f0  = c8 >> 2;                       // c0>>5
        const int row = ind + ((c8 & 3) << 4);         // i + 16*((c0>>3)&3)
#pragma unroll
        for (int d = 0; d < 3; ++d) {
            us8 hh, ll;
#pragma unroll
            for (int j = 0; j < 8; ++j) {
                float xv = x[j * 3 + d];
                __bf16 h = (__bf16)xv;
                hh[j] = __builtin_bit_cast(us, h);
                ll[j] = __builtin_bit_cast(us, (__bf16)(xv - (float)h));
            }
            const int off = (d * 4 + f0) * FS + row * 8;
            *(us8*)(dh + off) = hh;
            *(us8*)(dl + off) = ll;
        }
    }
    const float bzv = bz[bo], brv = br[bo];
    const f32x4 Z4 = {0.f, 0.f, 0.f, 0.f};

    // preload phase-1 B-frags before the barrier (global, no LDS dep)
    bf16x8 Bz[4], Brh[4], Brl[4];
    loadB4(pWhz, wb, Bz); loadB4(pWhrh, wb, Brh); loadB4(pWhrl, wb, Brl);
    __syncthreads();                                   // B1: tiles ready

    // ---- fused z (plain) + r (precise) ----
    f32x4 zacc[3] = {Z4, Z4, Z4}, racc[3] = {Z4, Z4, Z4};
    mm_zr(mvh, mvl, Bz, Brh, Brl, zacc, racc, ab);
    loadB4(pWiz, wb, Bz); loadB4(pWirh, wb, Brh); loadB4(pWirl, wb, Brl);
    mm_zr(vth, vtl, Bz, Brh, Brl, zacc, racc, ab);

    const int vbase = (bo >> 5) * FS + (rsub + (((bo >> 3) & 3) << 4)) * 8 + (bo & 7);
    float zz[4], vout[4][3];
#pragma unroll
    for (int q = 0; q < 4; ++q) {
        float h0 = zacc[0][q], h1 = zacc[1][q], h2 = zacc[2][q];
        zz[q] = 1.f / (1.f + __expf(-(sqrtf(h0 * h0 + h1 * h1 + h2 * h2) + bzv)));
        float r0 = racc[0][q], r1 = racc[1][q], r2 = racc[2][q];
        float rr = 1.f / (1.f + __expf(-(sqrtf(r0 * r0 + r1 * r1 + r2 * r2) + brv)));
        r_t[bo * 17 + rsub + q] = rr;
#pragma unroll
        for (int d = 0; d < 3; ++d) {
            int off = vbase + d * 4 * FS + q * 8;
            vout[q][d] = b2f(vth[off]) + b2f(vtl[off]);
        }
    }
    // preload delta-phase B (Whv) before rebuild barrier
    bf16x8 Bdh[4], Bdl[4];
    loadB4(pWhvh, wb, Bdh); loadB4(pWhvl, wb, Bdl);
    __syncthreads();                                   // B2: r_t visible; v reads done

    // ---- overwrite v tiles with r*v (hi/lo), full-slot us8 ----
#pragma unroll
    for (int it = 0; it < 2; ++it) {
        int s = tid + it * 512;
        if (s < 768) {                                 // wave-uniform guard
            int f = s >> 6, l = s & 63;
            int i = l & 15, cb = ((f & 3) << 5) + ((l >> 4) << 3);
            int off = f * FS + l * 8;
            us8 vh8 = *(const us8*)(vth + off);
            us8 vl8 = *(const us8*)(vtl + off);
            us8 oh, ol;
#pragma unroll
            for (int j = 0; j < 8; ++j) {
                float p = r_t[(cb + j) * 17 + i] * (b2f(vh8[j]) + b2f(vl8[j]));
                __bf16 h = (__bf16)p;
                oh[j] = __builtin_bit_cast(us, h);
                ol[j] = __builtin_bit_cast(us, (__bf16)(p - (float)h));
            }
            *(us8*)(vth + off) = oh;
            *(us8*)(vtl + off) = ol;
        }
    }
    __syncthreads();                                   // B3: rv visible

    // ---- delta = m_v @ Whv + (r*v) @ Wiv (precise) ----
    f32x4 dacc[3] = {Z4, Z4, Z4};
    mm_s(mvh, mvl, Bdh, Bdl, dacc, ab);
    loadB4(pWivh, wb, Bdh); loadB4(pWivl, wb, Bdl);
    mm_s(vth, vtl, Bdh, Bdl, dacc, ab);
    __syncthreads();                                   // B4: mv reads done

    // write delta hi/lo over dead m_v tiles
#pragma unroll
    for (int m = 0; m < 3; ++m)
#pragma unroll
    for (int q = 0; q < 4; ++q) {
        int off = vbase + m * 4 * FS + q * 8;
        float x = dacc[m][q];
        __bf16 h = (__bf16)x;
        mvh[off] = __builtin_bit_cast(us, h);
        mvl[off] = __builtin_bit_cast(us, (__bf16)(x - (float)h));
    }
    // preload QK-phase B before the barrier
    bf16x8 Bq[4], Bkh[4], Bkl[4];
    loadB4(pWq, wb, Bq); loadB4(pWkh, wb, Bkh); loadB4(pWkl, wb, Bkl);
    __syncthreads();                                   // B5: delta visible

    // ---- Q (plain), K (precise) ----
    f32x4 qacc[3] = {Z4, Z4, Z4}, kacc[3] = {Z4, Z4, Z4};
    mm_qk(mvh, mvl, Bq, Bkh, Bkl, qacc, kacc, ab);

    // ---- vn-leaky + gate + store ----
#pragma unroll
    for (int q = 0; q < 4; ++q) {
        const int i = rsub + q;
        float q0 = qacc[0][q], q1 = qacc[1][q], q2 = qacc[2][q];
        float k0 = kacc[0][q], k1 = kacc[1][q], k2 = kacc[2][q];
        float inner = fminf(q0 * k0 + q1 * k1 + q2 * k2, 0.f);
        float kn = sqrtf(k0 * k0 + k1 * k1 + k2 * k2) + 1e-7f;
        float s = inner / (kn * kn);
        float z = zz[q];
        float dv0 = 0.3f * dacc[0][q] + 0.7f * (q0 - s * k0);
        float dv1 = 0.3f * dacc[1][q] + 0.7f * (q1 - s * k1);
        float dv2 = 0.3f * dacc[2][q] + 0.7f * (q2 - s * k2);
        float* op = out + ((size_t)(n0 + i) * 128 + bo) * 3;
        op[0] = (1.f - z) * vout[q][0] + z * dv0;
        op[1] = (1.f - z) * vout[q][1] + z * dv1;
        op[2] = (1.f - z) * vout[q][2] + z * dv2;
    }
}

extern "C" void kernel_launch(void* const* d_in, const int* in_sizes, int n_in,
                              void* d_out, int out_size, void* d_ws, size_t ws_size,
                              hipStream_t stream) {
    (void)in_sizes; (void)n_in; (void)ws_size; (void)out_size;
    us* ws = (us*)d_ws;
    prep_weights<<<64, 256, 0, stream>>>(
        (const float*)d_in[2],  (const float*)d_in[3],
        (const float*)d_in[5],  (const float*)d_in[6],
        (const float*)d_in[8],  (const float*)d_in[9],
        (const float*)d_in[10], (const float*)d_in[11], ws);
    gru_vn_fused<<<NBLK, 512, 0, stream>>>(
        (const float*)d_in[0], (const float*)d_in[1],
        (const float*)d_in[4], (const float*)d_in[7],
        ws, (float*)d_out);
}